// Round 11
// baseline (6410.575 us; speedup 1.0000x reference)
//
#include <hip/hip_runtime.h>

#define NB    256
#define BT    1024
#define BATCH 128
#define HID   512
#define XSZ   64
#define SSZ   16
#define CPAD  32                 // ints per counter slot = 128B line
#define SPIN_MAX (1 << 17)

typedef unsigned int uint;
typedef unsigned long long ulong64;
typedef _Float16 half2v __attribute__((ext_vector_type(2)));

// agent-scope relaxed atomic load/store = sc-flagged, bypass stale L1/L2, no fences
#define AL8(p)    __hip_atomic_load((const ulong64*)(p), __ATOMIC_RELAXED, __HIP_MEMORY_SCOPE_AGENT)
#define AS4(p, v) __hip_atomic_store((uint*)(p), (v), __ATOMIC_RELAXED, __HIP_MEMORY_SCOPE_AGENT)

// ---------------- persistent device state ----------------
// act layout: [q][b] uint4, q = kpair/4 (64), b = batch (128); uint = f16 pair (cols 2m,2m+1)
__device__ __align__(16) uint4 g_h0Q[2][64 * 128];
__device__ __align__(16) uint4 g_h1Q[2][64 * 128];
__device__ __align__(16) float g_Wcomb[4 * HID * HID];   // 0.1 * W0s @ Wfc [2048][512]
__device__ int g_cnt[2100 * 4 * CPAD];                   // per-(phase pid, quarter) counters

// ---------------- helpers ----------------
__device__ __forceinline__ float sigf(float x) { return 1.f / (1.f + __expf(-x)); }
__device__ __forceinline__ float tanh_fast(float x) {
  float ax = fabsf(x); float e = __expf(-2.f * ax);
  return copysignf((1.f - e) / (1.f + e), x);
}
__device__ __forceinline__ uint pack_f16(float a, float b) {
  half2v h; h.x = (_Float16)a; h.y = (_Float16)b;
  return __builtin_bit_cast(uint, h);
}
__device__ __forceinline__ float2 up2(uint u) {
  half2v h = __builtin_bit_cast(half2v, u);
  return make_float2((float)h.x, (float)h.y);
}
__device__ __forceinline__ float fdot2(uint a, uint w, float c) {
#if __has_builtin(__builtin_amdgcn_fdot2)
  return __builtin_amdgcn_fdot2(__builtin_bit_cast(half2v, a),
                                __builtin_bit_cast(half2v, w), c, false);
#else
  float2 av = up2(a), wv = up2(w);
  return fmaf(av.x, wv.x, fmaf(av.y, wv.y, c));
#endif
}
__device__ __forceinline__ void dot8(uint a, uint4 w0, uint4 w1, float* acc) {
  acc[0] = fdot2(a, w0.x, acc[0]); acc[1] = fdot2(a, w0.y, acc[1]);
  acc[2] = fdot2(a, w0.z, acc[2]); acc[3] = fdot2(a, w0.w, acc[3]);
  acc[4] = fdot2(a, w1.x, acc[4]); acc[5] = fdot2(a, w1.y, acc[5]);
  acc[6] = fdot2(a, w1.z, acc[6]); acc[7] = fdot2(a, w1.w, acc[7]);
}
// dual-matrix dots over a 16-q-row slice: h loaded ONCE (2 chunks of 8 batched
// coherent loads), fed to two weight matrices -> accA, accB (8 gate rows each)
__device__ __forceinline__ void dots_dual(const uint4* __restrict__ apq,
                                          const uint*  __restrict__ wbA,
                                          const uint*  __restrict__ wbB,
                                          float* __restrict__ accA,
                                          float* __restrict__ accB) {
  const ulong64* ap = (const ulong64*)apq;
#pragma unroll
  for (int c = 0; c < 2; ++c) {
    ulong64 lo[8], hi[8];
#pragma unroll
    for (int i = 0; i < 8; ++i) {
      lo[i] = AL8(ap + (c * 8 + i) * 256);
      hi[i] = AL8(ap + (c * 8 + i) * 256 + 1);
    }
#pragma unroll
    for (int i = 0; i < 8; ++i) {
      const uint4* wA = (const uint4*)(wbA + 32 * (c * 8 + i));
      const uint4* wB = (const uint4*)(wbB + 32 * (c * 8 + i));
      uint a0 = (uint)lo[i], a1 = (uint)(lo[i] >> 32);
      uint a2 = (uint)hi[i], a3 = (uint)(hi[i] >> 32);
      dot8(a0, wA[0], wA[1], accA); dot8(a0, wB[0], wB[1], accB);
      dot8(a1, wA[2], wA[3], accA); dot8(a1, wB[2], wB[3], accB);
      dot8(a2, wA[4], wA[5], accA); dot8(a2, wB[4], wB[5], accB);
      dot8(a3, wA[6], wA[7], accA); dot8(a3, wB[6], wB[7], accB);
    }
  }
}

// quarter wait: both waves of a slice poll the quarter counter line directly
// (all lanes same address -> 1 line request per wave)
__device__ __forceinline__ void qwait(int pid, int qtr) {
  const int* cp = &g_cnt[(pid * 4 + qtr) * CPAD];
  int guard = 0;
  while (__hip_atomic_load(cp, __ATOMIC_RELAXED, __HIP_MEMORY_SCOPE_AGENT) < NB / 4) {
    __builtin_amdgcn_s_sleep(1);
    if (++guard > SPIN_MAX) break;
  }
  __builtin_amdgcn_sched_barrier(0);   // pin: no loads hoisted above the poll
}

// ---------------- setup ----------------
__global__ void setup_kernel(float* __restrict__ out, int T) {
  int idx = blockIdx.x * blockDim.x + threadIdx.x;
  int n   = gridDim.x * blockDim.x;
  uint* z0 = (uint*)g_h0Q;
  uint* z1 = (uint*)g_h1Q;
  for (int i = idx; i < 2 * 64 * 128 * 4; i += n) { z0[i] = 0u; z1[i] = 0u; }
  for (int t = idx; t < T; t += n) out[BATCH * T * SSZ + t] = (float)t * 0.1f;
  int ncnt = (2 * T + 2) * 4 * CPAD;
  for (int i = idx; i < ncnt; i += n) g_cnt[i] = 0;
}

// ---------------- Wcomb = 0.1 * W0s @ Wfc ----------------
__global__ void wcomb_kernel(const float* __restrict__ Wih0, const float* __restrict__ Wfc) {
  int idx = blockIdx.x * blockDim.x + threadIdx.x;
  int row = idx >> 9, k = idx & (HID - 1);
  float a = 0.f;
#pragma unroll
  for (int m = 0; m < SSZ; m++) a += Wih0[row * (XSZ + SSZ) + XSZ + m] * Wfc[m * HID + k];
  g_Wcomb[idx] = 0.1f * a;
}

// ---------------- persistent RNN kernel ----------------
__global__ __launch_bounds__(BT, 4) void persist_kernel(
    const float* __restrict__ x,    const float* __restrict__ s0,
    const float* __restrict__ Wih0, const float* __restrict__ Whh0,
    const float* __restrict__ bih0, const float* __restrict__ bhh0,
    const float* __restrict__ Wih1, const float* __restrict__ Whh1,
    const float* __restrict__ bih1, const float* __restrict__ bhh1,
    const float* __restrict__ Wfc,  const float* __restrict__ bfc,
    float* __restrict__ out, int T)
{
  __shared__ uint  lwT[4][256][8];    // [mat][kpair][row]: 0:Whh0 1:Wcomb 2:W1a 3:W1b
  __shared__ float gA[4][8][130];     // Wcomb.h1 partials   (phase A, ks4-7 -> epi A)
  __shared__ float gW[4][8][130];     // Whh0.h0 partials    (phase B, ks0-3 -> NEXT epi A)
  __shared__ float gB[8][8][130];     // [0..3] W1a.h0 (B), [4..7] W1b.h1 (A) -> epi B
  __shared__ uint  wfcP[16][268];     // Wfc f16 pairs, padded rows
  __shared__ int   arrive;            // monotonic per-wave epilogue arrivals

  const int bk   = blockIdx.x;
  const int tid  = threadIdx.x;
  const int ks   = tid >> 7;        // dot slice 0..7 (0-3: h0 mats, 4-7: h1 mats)
  const int bb   = tid & 127;       // dot batch column
  const int wv   = tid >> 6;        // wave 0..15
  const int lane = tid & 63;
  const int be   = (wv << 3) + (lane >> 3);  // epilogue batch (8 per wave)
  const int r    = lane & 7;                 // epilogue gate-row (g = r>>1, col = r&1)
  const int myq  = bk >> 6;                  // producer quarter

  if (tid == 0) arrive = 0;

  // ---- stage weights to LDS as f16 pairs (transposed: [kpair][row]) ----
  for (int e = tid; e < 4 * 256 * 8; e += BT) {
    int mat = e >> 11, kp = (e >> 3) & 255, rr = e & 7;
    int row = (rr >> 1) * HID + 2 * bk + (rr & 1);
    const float* src = (mat == 0) ? &Whh0[row * HID]
                     : (mat == 1) ? &g_Wcomb[row * HID]
                     : (mat == 2) ? &Wih1[row * HID] : &Whh1[row * HID];
    lwT[mat][kp][rr] = pack_f16(src[2 * kp], src[2 * kp + 1]);
  }
  for (int e = tid; e < 16 * 256; e += BT) {
    int fs_ = e >> 8, kp = e & 255;
    wfcP[fs_][kp] = pack_f16(Wfc[fs_ * HID + 2 * kp], Wfc[fs_ * HID + 2 * kp + 1]);
  }
  // zero gW (epi A at t=0 reads it: Whh0.h0_{-1} = 0)
  for (int e = tid; e < 4 * 8 * 130; e += BT) ((float*)gW)[e] = 0.f;

  // ---- per-thread epilogue constants (thread owns (be, r)) ----
  const int row_g = (r >> 1) * HID + 2 * bk + (r & 1);
  float sbase_t = bih0[row_g] + bhh0[row_g];
  {
    const float* wr = Wih0 + row_g * (XSZ + SSZ);
#pragma unroll 4
    for (int k = 0; k < XSZ; k++) sbase_t = fmaf(wr[k], x[be * XSZ + k], sbase_t);
  }
  float ucs_t = 0.f, u_t = 0.f;
  {
    const float* ws = Wih0 + row_g * (XSZ + SSZ) + XSZ;
#pragma unroll
    for (int m = 0; m < SSZ; m++) {
      ucs_t = fmaf(ws[m], bfc[m], ucs_t);
      u_t   = fmaf(ws[m], s0[be * SSZ + m], u_t);
    }
    ucs_t *= 0.1f;
    u_t   -= ucs_t;
  }
  const float b1_t = bih1[row_g] + bhh1[row_g];
  float c0_reg = 0.f, c1_reg = 0.f;

  // ---- fc lane state (wave 15 of blocks 128..255; one batch row each) ----
  const bool fcw = (bk >= 128) && (wv == 15);
  const int  fb = bk - 128, fs = lane & 15, fq = lane >> 4;
  float s_reg = 0.f, bfcj = 0.f;
  if (fcw && lane < SSZ) { s_reg = s0[fb * SSZ + lane]; bfcj = bfc[lane]; }

  auto fc_step = [&](int tt, const uint4* h1base) {
    const ulong64* hp = (const ulong64*)(h1base + fq * 16 * 128 + fb);
    ulong64 lo[16], hi[16];
#pragma unroll
    for (int i = 0; i < 16; ++i) {
      lo[i] = AL8(hp + i * 256);
      hi[i] = AL8(hp + i * 256 + 1);
    }
    const uint4* wp = (const uint4*)&wfcP[fs][fq * 64];
    float acc = 0.f;
#pragma unroll
    for (int i = 0; i < 16; ++i) {
      uint4 w = wp[i];
      acc = fdot2((uint)lo[i],         w.x, acc);
      acc = fdot2((uint)(lo[i] >> 32), w.y, acc);
      acc = fdot2((uint)hi[i],         w.z, acc);
      acc = fdot2((uint)(hi[i] >> 32), w.w, acc);
    }
    acc += __shfl_xor(acc, 16);
    acc += __shfl_xor(acc, 32);
    if (lane < SSZ) {
      float so = acc + bfcj;
      s_reg += 0.1f * so;
      out[fb * (T * SSZ) + tt * SSZ + fs] = s_reg;
      out[BATCH * T * SSZ + T + fb * (T * SSZ) + tt * SSZ + fs] = so;
    }
  };

  __syncthreads();

  int p = 0, ph = 0;
  for (int t = 0; t < T; ++t) {
    // ===== phase A : ks4-7 dual-dot on h1_{t-1} (Wcomb -> gA, W1b -> gB[4..7]) =====
    if (ks >= 4) {
      if (t > 0) qwait(2 * t, ks & 3);          // h1_{t-1} quarter ready
      float accA[8] = {0,0,0,0,0,0,0,0}, accB[8] = {0,0,0,0,0,0,0,0};
      dots_dual(g_h1Q[p] + (ks & 3) * 16 * 128 + bb,
                &lwT[1][(ks & 3) * 64][0], &lwT[3][(ks & 3) * 64][0], accA, accB);
#pragma unroll
      for (int r2 = 0; r2 < 8; r2++) { gA[ks - 4][r2][bb] = accA[r2]; gB[ks][r2][bb] = accB[r2]; }
    }
    __syncthreads();   // join1: gA/gW complete for epi A
    // ===== epilogue A (ALL waves): gates0_t -> h0_t =====
    {
      float s1 = gW[0][r][be] + gW[1][r][be] + gW[2][r][be] + gW[3][r][be];  // Whh0.h0_{t-1}
      float s2 = gA[0][r][be] + gA[1][r][be] + gA[2][r][be] + gA[3][r][be];  // Wcomb.h1_{t-1}
      u_t += s2 + ucs_t;
      float pre = sbase_t + s1 + u_t;
      float pf = __shfl_xor(pre, 2);
      float pg = __shfl_xor(pre, 4);
      float po = __shfl_xor(pre, 6);
      float c = sigf(pf) * c0_reg + sigf(pre) * tanh_fast(pg);
      if (r < 2) c0_reg = c;                     // owner lanes keep the cell
      float h = sigf(po) * tanh_fast(c);
      float hx = __shfl_xor(h, 1);
      if (r == 0)
        AS4(((uint*)&g_h0Q[p ^ 1][(bk >> 2) * 128 + be]) + (bk & 3), pack_f16(h, hx));
      asm volatile("s_waitcnt vmcnt(0)" ::: "memory");   // this wave's h0 stores drained
      if (lane == 0)
        __hip_atomic_fetch_add(&arrive, 1, __ATOMIC_RELEASE, __HIP_MEMORY_SCOPE_WORKGROUP);
      ++ph;
      if (tid == 0) {
        int g2 = 0;
        while (__hip_atomic_load(&arrive, __ATOMIC_ACQUIRE, __HIP_MEMORY_SCOPE_WORKGROUP) < 16 * ph) {
          __builtin_amdgcn_s_sleep(0);
          if (++g2 > SPIN_MAX) break;
        }
        __hip_atomic_fetch_add(&g_cnt[((2 * t + 1) * 4 + myq) * CPAD], 1,
                               __ATOMIC_RELAXED, __HIP_MEMORY_SCOPE_AGENT);
      }
    }
    // ===== phase B : ks0-3 dual-dot on h0_t (W1a -> gB[0..3], Whh0 -> gW) =====
    if (ks < 4) {
      qwait(2 * t + 1, ks);                     // h0_t quarter ready (incl. own block)
      float accA[8] = {0,0,0,0,0,0,0,0}, accB[8] = {0,0,0,0,0,0,0,0};
      dots_dual(g_h0Q[p ^ 1] + ks * 16 * 128 + bb,
                &lwT[2][ks * 64][0], &lwT[0][ks * 64][0], accA, accB);
#pragma unroll
      for (int r2 = 0; r2 < 8; r2++) { gB[ks][r2][bb] = accA[r2]; gW[ks][r2][bb] = accB[r2]; }
    } else {
      if (fcw && t > 0) fc_step(t - 1, g_h1Q[p]);   // fc for step t-1 in phase-B slack
    }
    __syncthreads();   // join2: gB complete for epi B
    // ===== epilogue B (ALL waves): gates1_t -> h1_t =====
    {
      float s1 = gB[0][r][be] + gB[1][r][be] + gB[2][r][be] + gB[3][r][be];  // W1a.h0_t
      float s2 = gB[4][r][be] + gB[5][r][be] + gB[6][r][be] + gB[7][r][be];  // W1b.h1_{t-1}
      float pre = b1_t + s1 + s2;
      float pf = __shfl_xor(pre, 2);
      float pg = __shfl_xor(pre, 4);
      float po = __shfl_xor(pre, 6);
      float c = sigf(pf) * c1_reg + sigf(pre) * tanh_fast(pg);
      if (r < 2) c1_reg = c;
      float h = sigf(po) * tanh_fast(c);
      float hx = __shfl_xor(h, 1);
      if (r == 0)
        AS4(((uint*)&g_h1Q[p ^ 1][(bk >> 2) * 128 + be]) + (bk & 3), pack_f16(h, hx));
      asm volatile("s_waitcnt vmcnt(0)" ::: "memory");
      if (lane == 0)
        __hip_atomic_fetch_add(&arrive, 1, __ATOMIC_RELEASE, __HIP_MEMORY_SCOPE_WORKGROUP);
      ++ph;
      if (tid == 0) {
        int g2 = 0;
        while (__hip_atomic_load(&arrive, __ATOMIC_ACQUIRE, __HIP_MEMORY_SCOPE_WORKGROUP) < 16 * ph) {
          __builtin_amdgcn_s_sleep(0);
          if (++g2 > SPIN_MAX) break;
        }
        __hip_atomic_fetch_add(&g_cnt[((2 * t + 2) * 4 + myq) * CPAD], 1,
                               __ATOMIC_RELAXED, __HIP_MEMORY_SCOPE_AGENT);
      }
    }
    p ^= 1;
  }

  // ---- final fc for step T-1 (needs all 4 quarters of h1_{T-1}) ----
  if (fcw) {
    for (int q = 0; q < 4; ++q) {
      int guard = 0;
      while (__hip_atomic_load(&g_cnt[(2 * T * 4 + q) * CPAD],
                               __ATOMIC_RELAXED, __HIP_MEMORY_SCOPE_AGENT) < NB / 4) {
        __builtin_amdgcn_s_sleep(2);
        if (++guard > SPIN_MAX) break;
      }
    }
    __builtin_amdgcn_sched_barrier(0);
    fc_step(T - 1, g_h1Q[p]);
  }
}

extern "C" void kernel_launch(void* const* d_in, const int* in_sizes, int n_in,
                              void* d_out, int out_size, void* d_ws, size_t ws_size,
                              hipStream_t stream) {
  const float* x    = (const float*)d_in[0];
  const float* s0   = (const float*)d_in[1];
  const float* Wih0 = (const float*)d_in[2];
  const float* Whh0 = (const float*)d_in[3];
  const float* bih0 = (const float*)d_in[4];
  const float* bhh0 = (const float*)d_in[5];
  const float* Wih1 = (const float*)d_in[6];
  const float* Whh1 = (const float*)d_in[7];
  const float* bih1 = (const float*)d_in[8];
  const float* bhh1 = (const float*)d_in[9];
  const float* Wfc  = (const float*)d_in[10];
  const float* bfc  = (const float*)d_in[11];
  float* out = (float*)d_out;

  const int T = out_size / (2 * BATCH * SSZ + 1);

  setup_kernel<<<64, 256, 0, stream>>>(out, T);
  wcomb_kernel<<<(4 * HID * HID) / 256, 256, 0, stream>>>(Wih0, Wfc);
  persist_kernel<<<NB, BT, 0, stream>>>(x, s0, Wih0, Whh0, bih0, bhh0,
                                        Wih1, Whh1, bih1, bhh1, Wfc, bfc, out, T);
}

// Round 13
// 5731.103 us; speedup vs baseline: 1.1186x; 1.1186x over previous
//
#include <hip/hip_runtime.h>

#define NB    256
#define BT    1024
#define BATCH 128
#define HID   512
#define XSZ   64
#define SSZ   16
#define CPAD  32                 // ints per counter slot = 128B line
#define SPIN_MAX (1 << 17)

typedef unsigned int uint;
typedef unsigned long long ulong64;
typedef _Float16 half2v __attribute__((ext_vector_type(2)));
typedef _Float16 f16x8  __attribute__((ext_vector_type(8)));
typedef float    f32x4  __attribute__((ext_vector_type(4)));

// agent-scope relaxed atomic load/store = sc-flagged, bypass stale L1/L2, no fences
#define AL8(p)    __hip_atomic_load((const ulong64*)(p), __ATOMIC_RELAXED, __HIP_MEMORY_SCOPE_AGENT)
#define AS4(p, v) __hip_atomic_store((uint*)(p), (v), __ATOMIC_RELAXED, __HIP_MEMORY_SCOPE_AGENT)

// ---------------- persistent device state ----------------
// act layout: [q][b] uint4, q = kpair/4 (64), b = batch (128); uint = f16 pair (cols 2m,2m+1)
__device__ __align__(16) uint4 g_h0Q[2][64 * 128];
__device__ __align__(16) uint4 g_h1Q[2][64 * 128];
__device__ __align__(16) float g_Wcomb[4 * HID * HID];   // 0.1 * W0s @ Wfc [2048][512]
__device__ int g_cnt[512 * CPAD];                        // per-phase arrival counters

// ---------------- helpers ----------------
__device__ __forceinline__ float sigf(float x) { return 1.f / (1.f + __expf(-x)); }
__device__ __forceinline__ float tanh_fast(float x) {
  float ax = fabsf(x); float e = __expf(-2.f * ax);
  return copysignf((1.f - e) / (1.f + e), x);
}
__device__ __forceinline__ uint pack_f16(float a, float b) {
  half2v h; h.x = (_Float16)a; h.y = (_Float16)b;
  return __builtin_bit_cast(uint, h);
}
__device__ __forceinline__ float2 up2(uint u) {
  half2v h = __builtin_bit_cast(half2v, u);
  return make_float2((float)h.x, (float)h.y);
}
__device__ __forceinline__ float fdot2(uint a, uint w, float c) {
#if __has_builtin(__builtin_amdgcn_fdot2)
  return __builtin_amdgcn_fdot2(__builtin_bit_cast(half2v, a),
                                __builtin_bit_cast(half2v, w), c, false);
#else
  float2 av = up2(a), wv = up2(w);
  return fmaf(av.x, wv.x, fmaf(av.y, wv.y, c));
#endif
}

// MFMA pass: D[batch 16][gaterow 16(8 real)] over K=512.
// A (h) lane l: batch m0+(l&15), k = (l>>4)*8 + j  -> one uint4 = 2 AL8 per k-tile.
// B (W) lane l: gaterow (l&15) (zero block for >=8), same (g,j)->k map.
// k-permutation consistency makes the exact HW k-order irrelevant.
__device__ __forceinline__ void mfma_pass(const uint4* __restrict__ actQ,
                                          const uint4* __restrict__ wmat,  // &lwM[mat][0][0][0]
                                          const uint4* __restrict__ zp,    // zero block
                                          int m0, int l15, int g, f32x4& acc) {
  const ulong64* ap = (const ulong64*)(actQ + g * 128 + m0 + l15);
  ulong64 lo[16], hh[16];
#pragma unroll
  for (int kt = 0; kt < 16; ++kt) {          // batched coherent loads (manual MLP)
    lo[kt] = AL8(ap + kt * 1024);
    hh[kt] = AL8(ap + kt * 1024 + 1);
  }
  const uint4* bp   = (l15 < 8) ? (wmat + g * 8 + l15) : zp;
  const int    bstp = (l15 < 8) ? 32 : 0;
#pragma unroll
  for (int kt = 0; kt < 16; ++kt) {
    uint4 av;
    av.x = (uint)lo[kt]; av.y = (uint)(lo[kt] >> 32);
    av.z = (uint)hh[kt]; av.w = (uint)(hh[kt] >> 32);
    f16x8 a = __builtin_bit_cast(f16x8, av);
    f16x8 b = __builtin_bit_cast(f16x8, bp[kt * bstp]);
    acc = __builtin_amdgcn_mfma_f32_16x16x32_f16(a, b, acc, 0, 0, 0);
  }
}

// gated waves poll the pid counter line directly (all lanes same addr = 1 line req)
__device__ __forceinline__ void gwait(int pid) {
  int guard = 0;
  while (__hip_atomic_load(&g_cnt[pid * CPAD], __ATOMIC_RELAXED, __HIP_MEMORY_SCOPE_AGENT) < 2 * NB) {
    __builtin_amdgcn_s_sleep(2);
    if (++guard > SPIN_MAX) break;
  }
  __builtin_amdgcn_sched_barrier(0);   // pin: no loads hoisted above the poll
}

// ---------------- setup ----------------
__global__ void setup_kernel(float* __restrict__ out, int T) {
  int idx = blockIdx.x * blockDim.x + threadIdx.x;
  int n   = gridDim.x * blockDim.x;
  uint* z0 = (uint*)g_h0Q;
  uint* z1 = (uint*)g_h1Q;
  for (int i = idx; i < 2 * 64 * 128 * 4; i += n) { z0[i] = 0u; z1[i] = 0u; }
  for (int t = idx; t < T; t += n) out[BATCH * T * SSZ + t] = (float)t * 0.1f;
  for (int i = idx; i < 512 * CPAD; i += n) g_cnt[i] = 0;
}

// ---------------- Wcomb = 0.1 * W0s @ Wfc ----------------
__global__ void wcomb_kernel(const float* __restrict__ Wih0, const float* __restrict__ Wfc) {
  int idx = blockIdx.x * blockDim.x + threadIdx.x;
  int row = idx >> 9, k = idx & (HID - 1);
  float a = 0.f;
#pragma unroll
  for (int m = 0; m < SSZ; m++) a += Wih0[row * (XSZ + SSZ) + XSZ + m] * Wfc[m * HID + k];
  g_Wcomb[idx] = 0.1f * a;
}

// ---------------- persistent RNN kernel (r8 protocol + MFMA dots) ----------------
__global__ __launch_bounds__(BT, 4) void persist_kernel(
    const float* __restrict__ x,    const float* __restrict__ s0,
    const float* __restrict__ Wih0, const float* __restrict__ Whh0,
    const float* __restrict__ bih0, const float* __restrict__ bhh0,
    const float* __restrict__ Wih1, const float* __restrict__ Whh1,
    const float* __restrict__ bih1, const float* __restrict__ bhh1,
    const float* __restrict__ Wfc,  const float* __restrict__ bfc,
    float* __restrict__ out, int T)
{
  __shared__ uint4 lwM[4][16][4][8];  // [mat][kt][g][row] B-fragments: 0:Whh0 1:Wcomb 2:W1a 3:W1b
  __shared__ uint4 zeroq;             // shared zero B-fragment for padded rows 8..15
  __shared__ float gbuf[2][8][132];   // [slot][row][batch] partials (reused across phases)
  __shared__ float sbase[8][128];     // x.W0x + biases
  __shared__ float u_s[8][128];       // u carry
  __shared__ float c0s[2][128], c1s[2][128];
  __shared__ uint  wfcP[16][268];     // Wfc f16 pairs, padded rows
  __shared__ float b1s[8], ucs[8];

  const int bk   = blockIdx.x;
  const int tid  = threadIdx.x;
  const int wv   = tid >> 6;        // wave 0..15
  const int lane = tid & 63;
  const int l15  = lane & 15;
  const int g    = lane >> 4;       // k-group 0..3
  const int m0   = (wv & 7) * 16;   // batch m-tile base
  const bool grp1 = (wv >= 8);      // h1-mat group (gated in phase A)

  if (tid == 0) zeroq = make_uint4(0u, 0u, 0u, 0u);

  // ---- stage weights to LDS as MFMA B-fragments ----
  for (int e = tid; e < 4 * 16 * 4 * 8; e += BT) {
    int mat = e >> 9, kt = (e >> 5) & 15, gg = (e >> 3) & 3, nn = e & 7;
    int row = (nn >> 1) * HID + 2 * bk + (nn & 1);
    const float* src = (mat == 0) ? &Whh0[row * HID]
                     : (mat == 1) ? &g_Wcomb[row * HID]
                     : (mat == 2) ? &Wih1[row * HID] : &Whh1[row * HID];
    int k0 = kt * 32 + gg * 8;
    uint4 v;
    v.x = pack_f16(src[k0 + 0], src[k0 + 1]);
    v.y = pack_f16(src[k0 + 2], src[k0 + 3]);
    v.z = pack_f16(src[k0 + 4], src[k0 + 5]);
    v.w = pack_f16(src[k0 + 6], src[k0 + 7]);
    lwM[mat][kt][gg][nn] = v;
  }
  for (int e = tid; e < 16 * 256; e += BT) {
    int fs_ = e >> 8, kp = e & 255;
    wfcP[fs_][kp] = pack_f16(Wfc[fs_ * HID + 2 * kp], Wfc[fs_ * HID + 2 * kp + 1]);
  }
  // ---- sbase = x.W0x + biases ----
  {
    int r = tid >> 7, bi = tid & 127;
    int row = (r >> 1) * HID + 2 * bk + (r & 1);
    float a = bih0[row] + bhh0[row];
    const float* wr = Wih0 + row * (XSZ + SSZ);
#pragma unroll 4
    for (int k = 0; k < XSZ; k++) a = fmaf(wr[k], x[bi * XSZ + k], a);
    sbase[r][bi] = a;
  }
  if (tid < 8) {
    int row = (tid >> 1) * HID + 2 * bk + (tid & 1);
    b1s[tid] = bih1[row] + bhh1[row];
    float uc = 0.f;
    const float* ws = Wih0 + row * (XSZ + SSZ) + XSZ;
#pragma unroll
    for (int m = 0; m < SSZ; m++) uc = fmaf(ws[m], bfc[m], uc);
    ucs[tid] = 0.1f * uc;
  }
  __syncthreads();
  // ---- u_s = W0s.s0 - ucs ; c = 0 ----
  if (tid < 128) {
#pragma unroll
    for (int r = 0; r < 8; r++) {
      int row = (r >> 1) * HID + 2 * bk + (r & 1);
      const float* ws = Wih0 + row * (XSZ + SSZ) + XSZ;
      float a = 0.f;
#pragma unroll
      for (int m = 0; m < SSZ; m++) a = fmaf(ws[m], s0[tid * SSZ + m], a);
      u_s[r][tid] = a - ucs[r];
    }
    c0s[0][tid] = 0.f; c0s[1][tid] = 0.f;
    c1s[0][tid] = 0.f; c1s[1][tid] = 0.f;
  }
  __syncthreads();

  // ---- fc lane state (wave 15 of blocks 128..255; one batch row each) ----
  const bool fcw = (bk >= 128) && (wv == 15);
  const int  fb = bk - 128, fs = lane & 15, fq = lane >> 4;
  float s_reg = 0.f, bfcj = 0.f;
  if (fcw && lane < SSZ) { s_reg = s0[fb * SSZ + lane]; bfcj = bfc[lane]; }

  auto fc_step = [&](int tt, const uint4* h1base) {
    const ulong64* hp = (const ulong64*)(h1base + fq * 16 * 128 + fb);
    ulong64 lo[16], hh[16];
#pragma unroll
    for (int i = 0; i < 16; ++i) {
      lo[i] = AL8(hp + i * 256);
      hh[i] = AL8(hp + i * 256 + 1);
    }
    const uint4* wp = (const uint4*)&wfcP[fs][fq * 64];
    float acc = 0.f;
#pragma unroll
    for (int i = 0; i < 16; ++i) {
      uint4 w = wp[i];
      acc = fdot2((uint)lo[i],         w.x, acc);
      acc = fdot2((uint)(lo[i] >> 32), w.y, acc);
      acc = fdot2((uint)hh[i],         w.z, acc);
      acc = fdot2((uint)(hh[i] >> 32), w.w, acc);
    }
    acc += __shfl_xor(acc, 16);
    acc += __shfl_xor(acc, 32);
    if (lane < SSZ) {
      float so = acc + bfcj;
      s_reg += 0.1f * so;
      out[fb * (T * SSZ) + tt * SSZ + fs] = s_reg;
      out[BATCH * T * SSZ + T + fb * (T * SSZ) + tt * SSZ + fs] = so;
    }
  };

  int p = 0;
  for (int t = 0; t < T; ++t) {
    // ===== phase A : waves 0-7 Whh0.h0_{t-1} (ungated), waves 8-15 Wcomb.h1_{t-1} =====
    if (grp1 && t > 0) gwait(2 * t);                    // h1_{t-1} globally stored
    {
      f32x4 acc = {0.f, 0.f, 0.f, 0.f};
      const uint4* actQ = grp1 ? g_h1Q[p] : g_h0Q[p];
      const uint4* wmat = &lwM[grp1 ? 1 : 0][0][0][0];
      mfma_pass(actQ, wmat, &zeroq, m0, l15, g, acc);
      if (l15 < 8) {
#pragma unroll
        for (int j = 0; j < 4; ++j) gbuf[grp1][l15][m0 + g * 4 + j] = acc[j];
      }
    }
    __syncthreads();
    // ===== epilogue A (tid<128): gates0_t -> h0_t =====
    if (tid < 128) {
      const int b = tid;
      float pre[8];
#pragma unroll
      for (int r = 0; r < 8; r++) {
        float s1 = gbuf[0][r][b];   // Whh0.h0_{t-1}
        float s2 = gbuf[1][r][b];   // Wcomb.h1_{t-1}
        float uu = u_s[r][b] + s2 + ucs[r];
        u_s[r][b] = uu;
        pre[r] = sbase[r][b] + s1 + uu;
      }
      float h[2];
#pragma unroll
      for (int jj = 0; jj < 2; jj++) {
        float c = c0s[jj][b];
        c = sigf(pre[2 + jj]) * c + sigf(pre[0 + jj]) * tanh_fast(pre[4 + jj]);
        c0s[jj][b] = c;
        h[jj] = sigf(pre[6 + jj]) * tanh_fast(c);
      }
      AS4(((uint*)&g_h0Q[p ^ 1][(bk >> 2) * 128 + b]) + (bk & 3), pack_f16(h[0], h[1]));
      asm volatile("s_waitcnt vmcnt(0)" ::: "memory");  // this wave's h0 at coherence point
      if ((tid & 63) == 0)
        __hip_atomic_fetch_add(&g_cnt[(2 * t + 1) * CPAD], 1,
                               __ATOMIC_RELAXED, __HIP_MEMORY_SCOPE_AGENT);
    }
    __syncthreads();

    // ===== phase B : waves 0-7 W1a.h0_t (gated), waves 8-15 W1b.h1_{t-1} =====
    if (!grp1) gwait(2 * t + 1);                        // h0_t globally stored
    {
      f32x4 acc = {0.f, 0.f, 0.f, 0.f};
      const uint4* actQ = grp1 ? g_h1Q[p] : g_h0Q[p ^ 1];
      const uint4* wmat = &lwM[grp1 ? 3 : 2][0][0][0];
      mfma_pass(actQ, wmat, &zeroq, m0, l15, g, acc);
      if (l15 < 8) {
#pragma unroll
        for (int j = 0; j < 4; ++j) gbuf[grp1][l15][m0 + g * 4 + j] = acc[j];
      }
    }
    __syncthreads();
    // ===== epilogue B (tid<128): gates1_t -> h1_t =====
    if (tid < 128) {
      const int b = tid;
      float pre[8];
#pragma unroll
      for (int r = 0; r < 8; r++)
        pre[r] = b1s[r] + gbuf[0][r][b] + gbuf[1][r][b];  // W1a.h0_t + W1b.h1_{t-1}
      float h[2];
#pragma unroll
      for (int jj = 0; jj < 2; jj++) {
        float c = c1s[jj][b];
        c = sigf(pre[2 + jj]) * c + sigf(pre[0 + jj]) * tanh_fast(pre[4 + jj]);
        c1s[jj][b] = c;
        h[jj] = sigf(pre[6 + jj]) * tanh_fast(c);
      }
      AS4(((uint*)&g_h1Q[p ^ 1][(bk >> 2) * 128 + b]) + (bk & 3), pack_f16(h[0], h[1]));
      asm volatile("s_waitcnt vmcnt(0)" ::: "memory");
      if ((tid & 63) == 0)
        __hip_atomic_fetch_add(&g_cnt[(2 * t + 2) * CPAD], 1,
                               __ATOMIC_RELAXED, __HIP_MEMORY_SCOPE_AGENT);
    }
    __syncthreads();

    // ---- fc for step t-1 (wave 15 tail; hides in its next gwait window) ----
    if (fcw && t > 0) fc_step(t - 1, g_h1Q[p]);         // h1_{t-1}: gated by 2t (phase A)

    p ^= 1;
  }

  // ---- final fc for step T-1 ----
  if (fcw) {
    gwait(2 * T);
    fc_step(T - 1, g_h1Q[p]);
  }
}

extern "C" void kernel_launch(void* const* d_in, const int* in_sizes, int n_in,
                              void* d_out, int out_size, void* d_ws, size_t ws_size,
                              hipStream_t stream) {
  const float* x    = (const float*)d_in[0];
  const float* s0   = (const float*)d_in[1];
  const float* Wih0 = (const float*)d_in[2];
  const float* Whh0 = (const float*)d_in[3];
  const float* bih0 = (const float*)d_in[4];
  const float* bhh0 = (const float*)d_in[5];
  const float* Wih1 = (const float*)d_in[6];
  const float* Whh1 = (const float*)d_in[7];
  const float* bih1 = (const float*)d_in[8];
  const float* bhh1 = (const float*)d_in[9];
  const float* Wfc  = (const float*)d_in[10];
  const float* bfc  = (const float*)d_in[11];
  float* out = (float*)d_out;

  const int T = out_size / (2 * BATCH * SSZ + 1);

  setup_kernel<<<64, 256, 0, stream>>>(out, T);
  wcomb_kernel<<<(4 * HID * HID) / 256, 256, 0, stream>>>(Wih0, Wfc);
  persist_kernel<<<NB, BT, 0, stream>>>(x, s0, Wih0, Whh0, bih0, bhh0,
                                        Wih1, Whh1, bih1, bhh1, Wfc, bfc, out, T);
}